// Round 6
// baseline (767.200 us; speedup 1.0000x reference)
//
#include <hip/hip_runtime.h>
#include <math.h>

typedef __fp16   fp16x2  __attribute__((ext_vector_type(2)));
typedef _Float16 half8   __attribute__((ext_vector_type(8)));
typedef float    floatx4 __attribute__((ext_vector_type(4)));

#define M_TOTAL 16384
#define K_DIM   2048
#define BM      32
#define BK      32
#define NT      256
#define NCHUNK  (K_DIM / BK)   // 64

// Pre-convert W (router||noise, fp32 [128][2048]) into ws as hi/lo f16,
// granule-major per 32-k chunk: chunk c = 8192 halves:
//   hi: [(g*128 + col)*8 + j]  (g=0..3 k-granule, col=0..127, j=0..7)
//   lo: same at +4096 halves
__global__ __launch_bounds__(256) void conv_w_kernel(
    const float* __restrict__ rw, const float* __restrict__ nw,
    _Float16* __restrict__ wsB)
{
    const int u   = blockIdx.x * 256 + threadIdx.x;  // 0..32767
    const int col = u & 127;
    const int g   = (u >> 7) & 3;
    const int c   = u >> 9;
    const float* srcRow = (col < 64) ? (rw + (size_t)col * K_DIM)
                                     : (nw + (size_t)(col - 64) * K_DIM);
    const float* src = srcRow + c * BK + g * 8;
    const float4 v0 = *(const float4*)src;
    const float4 v1 = *(const float4*)(src + 4);
    union { fp16x2 h[4]; uint4 q; } ph, pl;
    ph.h[0] = __builtin_amdgcn_cvt_pkrtz(v0.x, v0.y);
    ph.h[1] = __builtin_amdgcn_cvt_pkrtz(v0.z, v0.w);
    ph.h[2] = __builtin_amdgcn_cvt_pkrtz(v1.x, v1.y);
    ph.h[3] = __builtin_amdgcn_cvt_pkrtz(v1.z, v1.w);
    pl.h[0] = __builtin_amdgcn_cvt_pkrtz((v0.x - (float)ph.h[0].x) * 2048.0f,
                                         (v0.y - (float)ph.h[0].y) * 2048.0f);
    pl.h[1] = __builtin_amdgcn_cvt_pkrtz((v0.z - (float)ph.h[1].x) * 2048.0f,
                                         (v0.w - (float)ph.h[1].y) * 2048.0f);
    pl.h[2] = __builtin_amdgcn_cvt_pkrtz((v1.x - (float)ph.h[2].x) * 2048.0f,
                                         (v1.y - (float)ph.h[2].y) * 2048.0f);
    pl.h[3] = __builtin_amdgcn_cvt_pkrtz((v1.z - (float)ph.h[3].x) * 2048.0f,
                                         (v1.w - (float)ph.h[3].y) * 2048.0f);
    const size_t base = (size_t)c * 8192 + ((size_t)g * 128 + col) * 8;
    *(uint4*)&wsB[base]        = ph.q;
    *(uint4*)&wsB[base + 4096] = pl.q;
}

__device__ __forceinline__ void cvt_frag(const float4 v0, const float4 v1,
                                         half8* ah, half8* al) {
    union { fp16x2 h[4]; half8 v; } uh, ul;
    uh.h[0] = __builtin_amdgcn_cvt_pkrtz(v0.x, v0.y);
    uh.h[1] = __builtin_amdgcn_cvt_pkrtz(v0.z, v0.w);
    uh.h[2] = __builtin_amdgcn_cvt_pkrtz(v1.x, v1.y);
    uh.h[3] = __builtin_amdgcn_cvt_pkrtz(v1.z, v1.w);
    ul.h[0] = __builtin_amdgcn_cvt_pkrtz((v0.x - (float)uh.h[0].x) * 2048.0f,
                                         (v0.y - (float)uh.h[0].y) * 2048.0f);
    ul.h[1] = __builtin_amdgcn_cvt_pkrtz((v0.z - (float)uh.h[1].x) * 2048.0f,
                                         (v0.w - (float)uh.h[1].y) * 2048.0f);
    ul.h[2] = __builtin_amdgcn_cvt_pkrtz((v1.x - (float)uh.h[2].x) * 2048.0f,
                                         (v1.y - (float)uh.h[2].y) * 2048.0f);
    ul.h[3] = __builtin_amdgcn_cvt_pkrtz((v1.z - (float)uh.h[3].x) * 2048.0f,
                                         (v1.w - (float)uh.h[3].y) * 2048.0f);
    *ah = uh.v;
    *al = ul.v;
}

__global__ __launch_bounds__(NT, 2) void gemm_router_kernel(
    const float* __restrict__ x,
    const _Float16* __restrict__ wsB,
    const float* __restrict__ router_b,
    const float* __restrict__ noise_b,
    const float* __restrict__ noise_u,
    float* __restrict__ out)
{
    __shared__ struct {
        float Cs[32][132];
        float p1[32]; float p2[32]; int i1[32]; int i2[32];
    } sm;

    const int t    = threadIdx.x;
    const int lane = t & 63;
    const int w    = t >> 6;
    const int rowBase = blockIdx.x * BM;

    const int lr  = lane & 15;
    const int lg4 = lane >> 4;
    const int mt0 = (w & 1) * 16;    // wave's row half
    const int nt0 = (w >> 1) * 64;   // wave's col half

    // A: lane reads its own fragment's 8 fp32 per chunk (row = mt0+lr, k-granule lg4)
    const float* pa = x + (size_t)(rowBase + mt0 + lr) * K_DIM + lg4 * 8;
    // B: wsB is fragment-order; hi at pbh, lo at +4096 halves, chunk stride 8192
    const _Float16* pbh[4];
    #pragma unroll
    for (int ni = 0; ni < 4; ++ni)
        pbh[ni] = wsB + ((size_t)lg4 * 128 + nt0 + ni * 16 + lr) * 8;

    floatx4 acch[4], accx[4];
    #pragma unroll
    for (int ni = 0; ni < 4; ++ni) { acch[ni] = (floatx4)0.0f; accx[ni] = (floatx4)0.0f; }

    float4 a0s[2], a1s[2];
    uint4  bhs[2][4], bls[2][4];

    // prologue: chunks 0 and 1 into slots 0,1
    #pragma unroll
    for (int s = 0; s < 2; ++s) {
        a0s[s] = *(const float4*)(pa + s * BK);
        a1s[s] = *(const float4*)(pa + s * BK + 4);
        #pragma unroll
        for (int ni = 0; ni < 4; ++ni) {
            bhs[s][ni] = *(const uint4*)(pbh[ni] + (size_t)s * 8192);
            bls[s][ni] = *(const uint4*)(pbh[ni] + (size_t)s * 8192 + 4096);
        }
    }

    for (int c = 0; c < NCHUNK; ++c) {
        const int s = c & 1;

        // extract fragments for chunk c
        half8 ah, al;
        cvt_frag(a0s[s], a1s[s], &ah, &al);
        half8 bh[4], bl[4];
        #pragma unroll
        for (int ni = 0; ni < 4; ++ni) {
            union { uint4 q; half8 v; } cb;
            cb.q = bhs[s][ni]; bh[ni] = cb.v;
            cb.q = bls[s][ni]; bl[ni] = cb.v;
        }

        // distance-2 prefetch into the slot just freed
        if (c + 2 < NCHUNK) {
            a0s[s] = *(const float4*)(pa + (c + 2) * BK);
            a1s[s] = *(const float4*)(pa + (c + 2) * BK + 4);
            #pragma unroll
            for (int ni = 0; ni < 4; ++ni) {
                bhs[s][ni] = *(const uint4*)(pbh[ni] + (size_t)(c + 2) * 8192);
                bls[s][ni] = *(const uint4*)(pbh[ni] + (size_t)(c + 2) * 8192 + 4096);
            }
        }

        #pragma unroll
        for (int ni = 0; ni < 4; ++ni) {
            acch[ni] = __builtin_amdgcn_mfma_f32_16x16x32_f16(ah, bh[ni], acch[ni], 0, 0, 0);
            accx[ni] = __builtin_amdgcn_mfma_f32_16x16x32_f16(ah, bl[ni], accx[ni], 0, 0, 0);
            accx[ni] = __builtin_amdgcn_mfma_f32_16x16x32_f16(al, bh[ni], accx[ni], 0, 0, 0);
        }
    }

    // ---- fused epilogue ----
    #pragma unroll
    for (int ni = 0; ni < 4; ++ni) {
        const floatx4 v = acch[ni] + accx[ni] * (1.0f / 2048.0f);
        const int col = nt0 + ni * 16 + lr;
        #pragma unroll
        for (int reg = 0; reg < 4; ++reg)
            sm.Cs[mt0 + lg4 * 4 + reg][col] = v[reg];
    }
    __syncthreads();

    // per-row top-2: 8 threads/row, 8 experts each, shuffle merge
    {
        const int sr = t >> 3;          // row 0..31
        const int eg = (t & 7) * 8;     // expert base
        const int grow = rowBase + sr;
        const float* urow = noise_u + (size_t)grow * 64 + eg;
        const float4 u0 = *(const float4*)urow;
        const float4 u1 = *(const float4*)(urow + 4);
        const float uu[8] = {u0.x, u0.y, u0.z, u0.w, u1.x, u1.y, u1.z, u1.w};
        float v1 = -3.0e38f, v2 = -3.0e38f;
        int i1 = 0, i2 = 0;
        #pragma unroll
        for (int j = 0; j < 8; ++j) {
            const int e = eg + j;
            const float lg = sm.Cs[sr][e] + router_b[e];
            const float nz = sm.Cs[sr][64 + e] + noise_b[e];
            const float sp = fmaxf(nz, 0.0f) + log1pf(expf(-fabsf(nz)));
            const float nv = lg + sp * uu[j];
            if (nv > v1)      { v2 = v1; i2 = i1; v1 = nv; i1 = e; }
            else if (nv > v2) { v2 = nv; i2 = e; }
        }
        #pragma unroll
        for (int m = 1; m < 8; m <<= 1) {
            const float ov1 = __shfl_xor(v1, m, 64);
            const int   oi1 = __shfl_xor(i1, m, 64);
            const float ov2 = __shfl_xor(v2, m, 64);
            const int   oi2 = __shfl_xor(i2, m, 64);
            const bool takeO = (ov1 > v1) || (ov1 == v1 && oi1 < i1);
            const float t1v = takeO ? ov1 : v1;  const int t1i = takeO ? oi1 : i1;
            const float c2v = takeO ? v1 : ov1;  const int c2i = takeO ? i1 : oi1;
            const float c3v = takeO ? ov2 : v2;  const int c3i = takeO ? oi2 : i2;
            const bool k2 = (c3v > c2v) || (c3v == c2v && c3i < c2i);
            v1 = t1v; i1 = t1i;
            v2 = k2 ? c3v : c2v; i2 = k2 ? c3i : c2i;
        }
        if ((t & 7) == 0) {
            const float e2 = expf(v2 - v1);
            const float dn = 1.0f + e2;   // other 62 slots: exp(-1e30 - m) == 0
            sm.p1[sr] = 1.0f / dn;
            sm.p2[sr] = e2 / dn;
            sm.i1[sr] = i1;
            sm.i2[sr] = i2;
            float2 idx2;
            idx2.x = (float)i1;
            idx2.y = (float)i2;
            *(float2*)&out[(size_t)M_TOTAL * 64 + (size_t)grow * 2] = idx2;
        }
    }
    __syncthreads();

    // cooperative sparse-softmax write: 32 rows x 64 experts, 8 floats/thread
    {
        const int rr = t >> 3;
        const int e0 = (t & 7) * 8;
        const int g2 = rowBase + rr;
        const int j1 = sm.i1[rr], j2 = sm.i2[rr];
        const float q1 = sm.p1[rr], q2 = sm.p2[rr];
        float* orow = out + (size_t)g2 * 64;
        #pragma unroll
        for (int g = 0; g < 2; ++g) {
            const int b0 = e0 + g * 4;
            float4 v;
            v.x = (b0 + 0 == j1) ? q1 : (b0 + 0 == j2) ? q2 : 0.0f;
            v.y = (b0 + 1 == j1) ? q1 : (b0 + 1 == j2) ? q2 : 0.0f;
            v.z = (b0 + 2 == j1) ? q1 : (b0 + 2 == j2) ? q2 : 0.0f;
            v.w = (b0 + 3 == j1) ? q1 : (b0 + 3 == j2) ? q2 : 0.0f;
            *(float4*)&orow[b0] = v;
        }
    }
}

extern "C" void kernel_launch(void* const* d_in, const int* in_sizes, int n_in,
                              void* d_out, int out_size, void* d_ws, size_t ws_size,
                              hipStream_t stream) {
    const float* x  = (const float*)d_in[0];
    const float* rw = (const float*)d_in[1];
    const float* rb = (const float*)d_in[2];
    const float* nw = (const float*)d_in[3];
    const float* nb = (const float*)d_in[4];
    const float* nu = (const float*)d_in[5];
    float* out = (float*)d_out;
    _Float16* wsB = (_Float16*)d_ws;
    (void)in_sizes; (void)n_in; (void)out_size; (void)ws_size;

    hipLaunchKernelGGL(conv_w_kernel, dim3(128), dim3(256), 0, stream, rw, nw, wsB);
    hipLaunchKernelGGL(gemm_router_kernel, dim3(M_TOTAL / BM), dim3(NT), 0, stream,
                       x, wsB, rb, nb, nu, out);
}

// Round 7
// 421.876 us; speedup vs baseline: 1.8185x; 1.8185x over previous
//
#include <hip/hip_runtime.h>
#include <math.h>

typedef __fp16   fp16x2  __attribute__((ext_vector_type(2)));
typedef _Float16 half8   __attribute__((ext_vector_type(8)));
typedef float    floatx4 __attribute__((ext_vector_type(4)));

#define M_TOTAL 16384
#define K_DIM   2048
#define BM      32
#define BK      64
#define NT      256
#define NCHUNK  (K_DIM / BK)   // 32
#define SUBH    8192           // halves per 32-k sub-chunk of wsB
#define BUF_H   16384          // halves per LDS buffer (BK=64: 2 subs)

// Pre-convert W (router||noise, fp32 [128][2048]) into ws as hi/lo f16,
// granule-major per 32-k chunk: chunk c = 8192 halves:
//   hi: [(g*128 + col)*8 + j]  (g=0..3 k-granule, col=0..127, j=0..7)
//   lo: same at +4096 halves
__global__ __launch_bounds__(256) void conv_w_kernel(
    const float* __restrict__ rw, const float* __restrict__ nw,
    _Float16* __restrict__ wsB)
{
    const int u   = blockIdx.x * 256 + threadIdx.x;  // 0..32767
    const int col = u & 127;
    const int g   = (u >> 7) & 3;
    const int c   = u >> 9;
    const float* srcRow = (col < 64) ? (rw + (size_t)col * K_DIM)
                                     : (nw + (size_t)(col - 64) * K_DIM);
    const float* src = srcRow + c * 32 + g * 8;
    const float4 v0 = *(const float4*)src;
    const float4 v1 = *(const float4*)(src + 4);
    union { fp16x2 h[4]; uint4 q; } ph, pl;
    ph.h[0] = __builtin_amdgcn_cvt_pkrtz(v0.x, v0.y);
    ph.h[1] = __builtin_amdgcn_cvt_pkrtz(v0.z, v0.w);
    ph.h[2] = __builtin_amdgcn_cvt_pkrtz(v1.x, v1.y);
    ph.h[3] = __builtin_amdgcn_cvt_pkrtz(v1.z, v1.w);
    pl.h[0] = __builtin_amdgcn_cvt_pkrtz((v0.x - (float)ph.h[0].x) * 2048.0f,
                                         (v0.y - (float)ph.h[0].y) * 2048.0f);
    pl.h[1] = __builtin_amdgcn_cvt_pkrtz((v0.z - (float)ph.h[1].x) * 2048.0f,
                                         (v0.w - (float)ph.h[1].y) * 2048.0f);
    pl.h[2] = __builtin_amdgcn_cvt_pkrtz((v1.x - (float)ph.h[2].x) * 2048.0f,
                                         (v1.y - (float)ph.h[2].y) * 2048.0f);
    pl.h[3] = __builtin_amdgcn_cvt_pkrtz((v1.z - (float)ph.h[3].x) * 2048.0f,
                                         (v1.w - (float)ph.h[3].y) * 2048.0f);
    const size_t base = (size_t)c * SUBH + ((size_t)g * 128 + col) * 8;
    *(uint4*)&wsB[base]        = ph.q;
    *(uint4*)&wsB[base + 4096] = pl.q;
}

__device__ __forceinline__ void gl_lds16(const _Float16* g, _Float16* l) {
    __builtin_amdgcn_global_load_lds((const __attribute__((address_space(1))) void*)g,
                                     (__attribute__((address_space(3))) void*)l, 16, 0, 0);
}

__device__ __forceinline__ void cvt_frag(const float4 v0, const float4 v1,
                                         half8* ah, half8* al) {
    union { fp16x2 h[4]; half8 v; } uh, ul;
    uh.h[0] = __builtin_amdgcn_cvt_pkrtz(v0.x, v0.y);
    uh.h[1] = __builtin_amdgcn_cvt_pkrtz(v0.z, v0.w);
    uh.h[2] = __builtin_amdgcn_cvt_pkrtz(v1.x, v1.y);
    uh.h[3] = __builtin_amdgcn_cvt_pkrtz(v1.z, v1.w);
    ul.h[0] = __builtin_amdgcn_cvt_pkrtz((v0.x - (float)uh.h[0].x) * 2048.0f,
                                         (v0.y - (float)uh.h[0].y) * 2048.0f);
    ul.h[1] = __builtin_amdgcn_cvt_pkrtz((v0.z - (float)uh.h[1].x) * 2048.0f,
                                         (v0.w - (float)uh.h[1].y) * 2048.0f);
    ul.h[2] = __builtin_amdgcn_cvt_pkrtz((v1.x - (float)uh.h[2].x) * 2048.0f,
                                         (v1.y - (float)uh.h[2].y) * 2048.0f);
    ul.h[3] = __builtin_amdgcn_cvt_pkrtz((v1.z - (float)uh.h[3].x) * 2048.0f,
                                         (v1.w - (float)uh.h[3].y) * 2048.0f);
    *ah = uh.v;
    *al = ul.v;
}

__global__ __launch_bounds__(NT, 2) void gemm_router_kernel(
    const float* __restrict__ x,
    const _Float16* __restrict__ wsB,
    const float* __restrict__ router_b,
    const float* __restrict__ noise_b,
    const float* __restrict__ noise_u,
    float* __restrict__ out)
{
    __shared__ __align__(16) union {
        _Float16 S[2 * BUF_H];   // 64 KB: double-buffered B (hi/lo) only
        struct { float Cs[32][132]; float p1[32]; float p2[32]; int i1[32]; int i2[32]; } e;
    } sm;

    const int t    = threadIdx.x;
    const int lane = t & 63;
    const int w    = t >> 6;       // wave owns cols w*32..w*32+31 (all 32 rows)
    const int rowBase = blockIdx.x * BM;

    const int lr  = lane & 15;
    const int lg4 = lane >> 4;

    // A: per-lane register loads; wave covers rows via 2 m-frags (lr, lr+16)
    const float* paBase = x + (size_t)(rowBase + lr) * K_DIM + lg4 * 8;

    // B staging: thread handles segments n = w*4+i of each 32-k sub
    const int nseg = w * 4;

    floatx4 acch[2][2], accx[2][2];
    #pragma unroll
    for (int mi = 0; mi < 2; ++mi)
        #pragma unroll
        for (int ni = 0; ni < 2; ++ni) {
            acch[mi][ni] = (floatx4)0.0f;
            accx[mi][ni] = (floatx4)0.0f;
        }

    float4 aR[2][8];

    // prologue: chunk 0 -> buf0 / aR[0]
    #pragma unroll
    for (int s = 0; s < 2; ++s)
        #pragma unroll
        for (int i = 0; i < 4; ++i)
            gl_lds16(wsB + (size_t)s * SUBH + (nseg + i) * 512 + lane * 8,
                     &sm.S[s * SUBH + (nseg + i) * 512]);
    #pragma unroll
    for (int s = 0; s < 2; ++s)
        #pragma unroll
        for (int mi = 0; mi < 2; ++mi) {
            const float* p = paBase + (size_t)(mi * 16) * K_DIM + s * 32;
            aR[0][s * 4 + mi * 2 + 0] = *(const float4*)p;
            aR[0][s * 4 + mi * 2 + 1] = *(const float4*)(p + 4);
        }

    for (int c = 0; c < NCHUNK; ++c) {
        __syncthreads();   // B(c) DMA complete; previous-buffer reads done
        const int pcur = c & 1;
        _Float16* buf  = sm.S + pcur * BUF_H;

        if (c + 1 < NCHUNK) {
            const int pn = (c + 1) & 1;
            _Float16* bufn = sm.S + pn * BUF_H;
            const _Float16* wc = wsB + (size_t)(2 * (c + 1)) * SUBH;
            #pragma unroll
            for (int s = 0; s < 2; ++s)
                #pragma unroll
                for (int i = 0; i < 4; ++i)
                    gl_lds16(wc + (size_t)s * SUBH + (nseg + i) * 512 + lane * 8,
                             bufn + s * SUBH + (nseg + i) * 512);
            #pragma unroll
            for (int s = 0; s < 2; ++s)
                #pragma unroll
                for (int mi = 0; mi < 2; ++mi) {
                    const float* p = paBase + (size_t)(mi * 16) * K_DIM + (c + 1) * BK + s * 32;
                    aR[pn][s * 4 + mi * 2 + 0] = *(const float4*)p;
                    aR[pn][s * 4 + mi * 2 + 1] = *(const float4*)(p + 4);
                }
        }

        #pragma unroll
        for (int s = 0; s < 2; ++s) {
            half8 bh[2], bl[2];
            #pragma unroll
            for (int ni = 0; ni < 2; ++ni) {
                const int bo = s * SUBH + (lg4 * 128 + w * 32 + ni * 16 + lr) * 8;
                bh[ni] = *(const half8*)&buf[bo];
                bl[ni] = *(const half8*)&buf[bo + 4096];
            }
            half8 ah[2], al[2];
            #pragma unroll
            for (int mi = 0; mi < 2; ++mi)
                cvt_frag(aR[pcur][s * 4 + mi * 2], aR[pcur][s * 4 + mi * 2 + 1],
                         &ah[mi], &al[mi]);
            #pragma unroll
            for (int mi = 0; mi < 2; ++mi)
                #pragma unroll
                for (int ni = 0; ni < 2; ++ni) {
                    acch[mi][ni] = __builtin_amdgcn_mfma_f32_16x16x32_f16(ah[mi], bh[ni], acch[mi][ni], 0, 0, 0);
                    accx[mi][ni] = __builtin_amdgcn_mfma_f32_16x16x32_f16(ah[mi], bl[ni], accx[mi][ni], 0, 0, 0);
                    accx[mi][ni] = __builtin_amdgcn_mfma_f32_16x16x32_f16(al[mi], bh[ni], accx[mi][ni], 0, 0, 0);
                }
        }
    }

    // ---- fused epilogue ----
    // last chunk (c=31) read buf1 (bytes 32K..64K); Cs lives in bytes 0..~17K -> no race
    #pragma unroll
    for (int mi = 0; mi < 2; ++mi)
        #pragma unroll
        for (int ni = 0; ni < 2; ++ni) {
            const floatx4 v = acch[mi][ni] + accx[mi][ni] * (1.0f / 2048.0f);
            const int col = w * 32 + ni * 16 + lr;
            #pragma unroll
            for (int reg = 0; reg < 4; ++reg)
                sm.e.Cs[mi * 16 + lg4 * 4 + reg][col] = v[reg];
        }
    __syncthreads();

    // per-row top-2: 8 threads/row, 8 experts each, shuffle merge
    {
        const int sr = t >> 3;          // row 0..31
        const int eg = (t & 7) * 8;     // expert base
        const int grow = rowBase + sr;
        const float* urow = noise_u + (size_t)grow * 64 + eg;
        const float4 u0 = *(const float4*)urow;
        const float4 u1 = *(const float4*)(urow + 4);
        const float uu[8] = {u0.x, u0.y, u0.z, u0.w, u1.x, u1.y, u1.z, u1.w};
        float v1 = -3.0e38f, v2 = -3.0e38f;
        int i1 = 0, i2 = 0;
        #pragma unroll
        for (int j = 0; j < 8; ++j) {
            const int e = eg + j;
            const float lg = sm.e.Cs[sr][e] + router_b[e];
            const float nz = sm.e.Cs[sr][64 + e] + noise_b[e];
            const float sp = fmaxf(nz, 0.0f) + log1pf(expf(-fabsf(nz)));
            const float nv = lg + sp * uu[j];
            if (nv > v1)      { v2 = v1; i2 = i1; v1 = nv; i1 = e; }
            else if (nv > v2) { v2 = nv; i2 = e; }
        }
        #pragma unroll
        for (int m = 1; m < 8; m <<= 1) {
            const float ov1 = __shfl_xor(v1, m, 64);
            const int   oi1 = __shfl_xor(i1, m, 64);
            const float ov2 = __shfl_xor(v2, m, 64);
            const int   oi2 = __shfl_xor(i2, m, 64);
            const bool takeO = (ov1 > v1) || (ov1 == v1 && oi1 < i1);
            const float t1v = takeO ? ov1 : v1;  const int t1i = takeO ? oi1 : i1;
            const float c2v = takeO ? v1 : ov1;  const int c2i = takeO ? i1 : oi1;
            const float c3v = takeO ? ov2 : v2;  const int c3i = takeO ? oi2 : i2;
            const bool k2 = (c3v > c2v) || (c3v == c2v && c3i < c2i);
            v1 = t1v; i1 = t1i;
            v2 = k2 ? c3v : c2v; i2 = k2 ? c3i : c2i;
        }
        if ((t & 7) == 0) {
            const float e2 = expf(v2 - v1);
            const float dn = 1.0f + e2;   // other 62 slots: exp(-1e30 - m) == 0
            sm.e.p1[sr] = 1.0f / dn;
            sm.e.p2[sr] = e2 / dn;
            sm.e.i1[sr] = i1;
            sm.e.i2[sr] = i2;
            float2 idx2;
            idx2.x = (float)i1;
            idx2.y = (float)i2;
            *(float2*)&out[(size_t)M_TOTAL * 64 + (size_t)grow * 2] = idx2;
        }
    }
    __syncthreads();

    // cooperative sparse-softmax write: 32 rows x 64 experts, 8 floats/thread
    {
        const int rr = t >> 3;
        const int e0 = (t & 7) * 8;
        const int g2 = rowBase + rr;
        const int j1 = sm.e.i1[rr], j2 = sm.e.i2[rr];
        const float q1 = sm.e.p1[rr], q2 = sm.e.p2[rr];
        float* orow = out + (size_t)g2 * 64;
        #pragma unroll
        for (int g = 0; g < 2; ++g) {
            const int b0 = e0 + g * 4;
            float4 v;
            v.x = (b0 + 0 == j1) ? q1 : (b0 + 0 == j2) ? q2 : 0.0f;
            v.y = (b0 + 1 == j1) ? q1 : (b0 + 1 == j2) ? q2 : 0.0f;
            v.z = (b0 + 2 == j1) ? q1 : (b0 + 2 == j2) ? q2 : 0.0f;
            v.w = (b0 + 3 == j1) ? q1 : (b0 + 3 == j2) ? q2 : 0.0f;
            *(float4*)&orow[b0] = v;
        }
    }
}

extern "C" void kernel_launch(void* const* d_in, const int* in_sizes, int n_in,
                              void* d_out, int out_size, void* d_ws, size_t ws_size,
                              hipStream_t stream) {
    const float* x  = (const float*)d_in[0];
    const float* rw = (const float*)d_in[1];
    const float* rb = (const float*)d_in[2];
    const float* nw = (const float*)d_in[3];
    const float* nb = (const float*)d_in[4];
    const float* nu = (const float*)d_in[5];
    float* out = (float*)d_out;
    _Float16* wsB = (_Float16*)d_ws;
    (void)in_sizes; (void)n_in; (void)out_size; (void)ws_size;

    hipLaunchKernelGGL(conv_w_kernel, dim3(128), dim3(256), 0, stream, rw, nw, wsB);
    hipLaunchKernelGGL(gemm_router_kernel, dim3(M_TOTAL / BM), dim3(NT), 0, stream,
                       x, wsB, rb, nb, nu, out);
}